// Round 1
// baseline (665.558 us; speedup 1.0000x reference)
//
#include <hip/hip_runtime.h>
#include <hip/hip_bf16.h>

// ---------------------------------------------------------------------------
// GNN: h = relu(GCN(x)); h = relu(GAT(h)); h = relu(GCN(h)); h = relu(GAT(h));
//      z = h @ Wo + bo.  Outputs: [h (N*128), z (N*64)] fp32.
// Strategy: build CSR (sorted by dst) per call via counting sort, then
// wave-per-node aggregation (deterministic per-segment order not needed for
// fp32 tolerance, but CSR avoids 435M global fp32 atomics). GEMMs are fp32
// LDS-tiled (no fp32 MFMA on CDNA4).
// ---------------------------------------------------------------------------

#define WAVE 64

// ------------------------------ graph build --------------------------------

__global__ void k_zero_i32(int* __restrict__ p, int n) {
    int i = blockIdx.x * 256 + threadIdx.x;
    if (i < n) p[i] = 0;
}

// in-degree histogram over dst (edges [0,E) from edge_index, [E,Et) self loops)
__global__ void k_hist(const int* __restrict__ ei, int* __restrict__ deg,
                       int E, int Et) {
    int e = blockIdx.x * 256 + threadIdx.x;
    if (e >= Et) return;
    int d = (e < E) ? ei[E + e] : (e - E);
    atomicAdd(&deg[d], 1);
}

// per-block reduce of deg -> block sums
__global__ void k_scan1(const int* __restrict__ deg, int* __restrict__ bs, int n) {
    __shared__ int tmp[256];
    int tid = threadIdx.x;
    int gid = blockIdx.x * 256 + tid;
    tmp[tid] = (gid < n) ? deg[gid] : 0;
    __syncthreads();
    for (int off = 128; off > 0; off >>= 1) {
        if (tid < off) tmp[tid] += tmp[tid + off];
        __syncthreads();
    }
    if (tid == 0) bs[blockIdx.x] = tmp[0];
}

// exclusive scan of block sums (nb <= 256) in one block
__global__ void k_scan2(int* __restrict__ bs, int nb) {
    __shared__ int tmp[256];
    int tid = threadIdx.x;
    int v = (tid < nb) ? bs[tid] : 0;
    tmp[tid] = v;
    __syncthreads();
    for (int off = 1; off < 256; off <<= 1) {
        int t = (tid >= off) ? tmp[tid - off] : 0;
        __syncthreads();
        tmp[tid] += t;
        __syncthreads();
    }
    if (tid < nb) bs[tid] = tmp[tid] - v;   // exclusive
}

// block-local exclusive scan + block offset -> row_ptr, cursor, inv=rsqrt(deg)
__global__ void k_scan3(const int* __restrict__ deg, const int* __restrict__ bs,
                        int* __restrict__ rowp, int* __restrict__ cur,
                        float* __restrict__ inv, int n, int total) {
    __shared__ int tmp[256];
    int tid = threadIdx.x;
    int gid = blockIdx.x * 256 + tid;
    int v = (gid < n) ? deg[gid] : 0;
    tmp[tid] = v;
    __syncthreads();
    for (int off = 1; off < 256; off <<= 1) {
        int t = (tid >= off) ? tmp[tid - off] : 0;
        __syncthreads();
        tmp[tid] += t;
        __syncthreads();
    }
    if (gid < n) {
        int rp = bs[blockIdx.x] + tmp[tid] - v;
        rowp[gid] = rp;
        cur[gid] = rp;
        inv[gid] = rsqrtf((float)v);
    }
    if (gid == 0) rowp[n] = total;
}

// place src ids grouped by dst
__global__ void k_scatter(const int* __restrict__ ei, int* __restrict__ cur,
                          int* __restrict__ esrc, int E, int Et) {
    int e = blockIdx.x * 256 + threadIdx.x;
    if (e >= Et) return;
    int s, d;
    if (e < E) { s = ei[e]; d = ei[E + e]; }
    else       { s = d = e - E; }
    int pos = atomicAdd(&cur[d], 1);
    esrc[pos] = s;
}

// ------------------------------ GEMM (fp32) --------------------------------
// out[M x NC] = A[M x 128] @ W[128 x NC] (+bias) (opt relu).
// Tile: TR=4096/NC rows x NC cols, 256 threads, 4x4 register blocking.
// W staged in two 64-row K-halves to keep LDS < 50 KB.

template <int NC>
__global__ __launch_bounds__(256) void gemm_k128(
    const float* __restrict__ A, const float* __restrict__ W,
    const float* __restrict__ bias, float* __restrict__ out,
    int M, int do_relu) {
    constexpr int TR = 4096 / NC;   // 32 (NC=128) or 64 (NC=64)
    constexpr int CG = NC / 4;      // col groups of 4
    constexpr int AP = 132;         // padded A row stride (16B aligned, banks offset)
    __shared__ float Ws[64 * NC];
    __shared__ float As[TR * AP];

    const int tid = threadIdx.x;
    const int cg = tid % CG;
    const int rg = tid / CG;
    const int row0 = blockIdx.x * TR;

    // stage A tile (zero-pad rows past M)
    for (int i = tid; i < TR * 32; i += 256) {
        int r = i >> 5, c4 = i & 31;
        int gr = row0 + r;
        float4 v = make_float4(0.f, 0.f, 0.f, 0.f);
        if (gr < M) v = ((const float4*)A)[(size_t)gr * 32 + c4];
        *((float4*)(As + r * AP + c4 * 4)) = v;
    }

    float acc[4][4] = {{0.f}};
    for (int half = 0; half < 2; ++half) {
        __syncthreads();   // As ready (h0) / previous Ws reads done (h1)
        for (int i = tid; i < 64 * NC / 4; i += 256)
            ((float4*)Ws)[i] = ((const float4*)W)[half * (64 * NC / 4) + i];
        __syncthreads();
#pragma unroll
        for (int k4 = 0; k4 < 16; ++k4) {
            float4 aa[4];
#pragma unroll
            for (int i = 0; i < 4; ++i)
                aa[i] = *((const float4*)(As + (rg * 4 + i) * AP + half * 64 + k4 * 4));
#pragma unroll
            for (int kk = 0; kk < 4; ++kk) {
                float4 w = ((const float4*)Ws)[(k4 * 4 + kk) * CG + cg];
#pragma unroll
                for (int i = 0; i < 4; ++i) {
                    float av = ((const float*)&aa[i])[kk];
                    acc[i][0] = fmaf(av, w.x, acc[i][0]);
                    acc[i][1] = fmaf(av, w.y, acc[i][1]);
                    acc[i][2] = fmaf(av, w.z, acc[i][2]);
                    acc[i][3] = fmaf(av, w.w, acc[i][3]);
                }
            }
        }
    }

    float4 b4 = make_float4(0.f, 0.f, 0.f, 0.f);
    if (bias) b4 = ((const float4*)bias)[cg];
#pragma unroll
    for (int i = 0; i < 4; ++i) {
        int gr = row0 + rg * 4 + i;
        if (gr < M) {
            float4 r;
            r.x = acc[i][0] + b4.x;
            r.y = acc[i][1] + b4.y;
            r.z = acc[i][2] + b4.z;
            r.w = acc[i][3] + b4.w;
            if (do_relu) {
                r.x = fmaxf(r.x, 0.f); r.y = fmaxf(r.y, 0.f);
                r.z = fmaxf(r.z, 0.f); r.w = fmaxf(r.w, 0.f);
            }
            ((float4*)out)[(size_t)gr * CG + cg] = r;
        }
    }
}

// --------------------------- aggregation kernels ---------------------------
// One wave (64 lanes) per destination node; lane l owns features l and l+64.

__global__ __launch_bounds__(256) void k_gcn_agg(
    const float* __restrict__ xw, const int* __restrict__ rowp,
    const int* __restrict__ esrc, const float* __restrict__ inv,
    const float* __restrict__ bias, float* __restrict__ out, int Nn) {
    int gid = blockIdx.x * 256 + threadIdx.x;
    int n = gid >> 6, lane = gid & 63;
    if (n >= Nn) return;
    int beg = rowp[n], end = rowp[n + 1];
    float invd = inv[n];
    float a0 = 0.f, a1 = 0.f;
    for (int base = beg; base < end; base += WAVE) {
        int e = base + lane;
        bool valid = (e < end);
        int sid = valid ? esrc[e] : 0;
        float c = valid ? invd * inv[sid] : 0.f;
        int cnt = min(WAVE, end - base);
        for (int j = 0; j < cnt; ++j) {
            int s = __shfl(sid, j);
            float cj = __shfl(c, j);
            const float* row = xw + (size_t)s * 128;
            a0 = fmaf(cj, row[lane], a0);
            a1 = fmaf(cj, row[lane + 64], a1);
        }
    }
    out[(size_t)n * 128 + lane]      = fmaxf(a0 + bias[lane], 0.f);
    out[(size_t)n * 128 + 64 + lane] = fmaxf(a1 + bias[lane + 64], 0.f);
}

// per-node attention logits: s_out[n] = xw[n]·asrc, d_out[n] = xw[n]·adst
__global__ __launch_bounds__(256) void k_alpha(
    const float* __restrict__ xw, const float* __restrict__ asrc,
    const float* __restrict__ adst, float* __restrict__ s_out,
    float* __restrict__ d_out_, int Nn) {
    int gid = blockIdx.x * 256 + threadIdx.x;
    int n = gid >> 6, lane = gid & 63;
    if (n >= Nn) return;
    const float* row = xw + (size_t)n * 128;
    float x0 = row[lane], x1 = row[lane + 64];
    float s = fmaf(x1, asrc[lane + 64], x0 * asrc[lane]);
    float d = fmaf(x1, adst[lane + 64], x0 * adst[lane]);
#pragma unroll
    for (int off = 32; off > 0; off >>= 1) {
        s += __shfl_xor(s, off);
        d += __shfl_xor(d, off);
    }
    if (lane == 0) { s_out[n] = s; d_out_[n] = d; }
}

__global__ __launch_bounds__(256) void k_gat_agg(
    const float* __restrict__ xw, const int* __restrict__ rowp,
    const int* __restrict__ esrc, const float* __restrict__ as_,
    const float* __restrict__ ad_, const float* __restrict__ bias,
    float* __restrict__ out, int Nn) {
    int gid = blockIdx.x * 256 + threadIdx.x;
    int n = gid >> 6, lane = gid & 63;
    if (n >= Nn) return;
    int beg = rowp[n], end = rowp[n + 1];
    float adn = ad_[n];

    // pass 1: segment max of leaky_relu(as[src] + ad[n])
    float m = -1e30f;
    for (int e = beg + lane; e < end; e += WAVE) {
        float v = as_[esrc[e]] + adn;
        v = (v > 0.f) ? v : 0.2f * v;
        m = fmaxf(m, v);
    }
#pragma unroll
    for (int off = 32; off > 0; off >>= 1) m = fmaxf(m, __shfl_xor(m, off));

    // pass 2: denom
    float ssum = 0.f;
    for (int e = beg + lane; e < end; e += WAVE) {
        float v = as_[esrc[e]] + adn;
        v = (v > 0.f) ? v : 0.2f * v;
        ssum += __expf(v - m);
    }
#pragma unroll
    for (int off = 32; off > 0; off >>= 1) ssum += __shfl_xor(ssum, off);
    float rden = 1.f / ssum;

    // pass 3: weighted aggregation
    float a0 = 0.f, a1 = 0.f;
    for (int base = beg; base < end; base += WAVE) {
        int e = base + lane;
        bool valid = (e < end);
        int sid = valid ? esrc[e] : 0;
        float wgt = 0.f;
        if (valid) {
            float v = as_[sid] + adn;
            v = (v > 0.f) ? v : 0.2f * v;
            wgt = __expf(v - m) * rden;
        }
        int cnt = min(WAVE, end - base);
        for (int j = 0; j < cnt; ++j) {
            int s = __shfl(sid, j);
            float wj = __shfl(wgt, j);
            const float* row = xw + (size_t)s * 128;
            a0 = fmaf(wj, row[lane], a0);
            a1 = fmaf(wj, row[lane + 64], a1);
        }
    }
    out[(size_t)n * 128 + lane]      = fmaxf(a0 + bias[lane], 0.f);
    out[(size_t)n * 128 + 64 + lane] = fmaxf(a1 + bias[lane + 64], 0.f);
}

// ------------------------------- launch ------------------------------------

extern "C" void kernel_launch(void* const* d_in, const int* in_sizes, int n_in,
                              void* d_out, int out_size, void* d_ws, size_t ws_size,
                              hipStream_t stream) {
    const float* x   = (const float*)d_in[0];
    const int*   ei  = (const int*)d_in[1];
    const float* W1  = (const float*)d_in[2];
    const float* b1  = (const float*)d_in[3];
    const float* Wg1 = (const float*)d_in[4];
    const float* as1 = (const float*)d_in[5];
    const float* ad1 = (const float*)d_in[6];
    const float* bg1 = (const float*)d_in[7];
    const float* W2  = (const float*)d_in[8];
    const float* b2  = (const float*)d_in[9];
    const float* Wg2 = (const float*)d_in[10];
    const float* as2 = (const float*)d_in[11];
    const float* ad2 = (const float*)d_in[12];
    const float* bg2 = (const float*)d_in[13];
    const float* Wo  = (const float*)d_in[14];
    const float* bo  = (const float*)d_in[15];

    const int Nn = in_sizes[0] / 128;   // 50000
    const int E  = in_sizes[1] / 2;     // 800000
    const int Et = E + Nn;              // +self loops
    const int H  = 128;

    float* outH = (float*)d_out;                 // h  (N x 128) — also h ping buffer
    float* outZ = outH + (size_t)Nn * H;         // z  (N x 64)

    // workspace carve (~30 MB)
    char* p = (char*)d_ws;
    auto carve = [&](size_t bytes) {
        char* r = p;
        p += (bytes + 255) & ~(size_t)255;
        return r;
    };
    float* bufA  = (float*)carve((size_t)Nn * H * sizeof(float));  // xw buffer
    float* alS   = (float*)carve((size_t)Nn * sizeof(float));
    float* alD   = (float*)carve((size_t)Nn * sizeof(float));
    float* inv   = (float*)carve((size_t)Nn * sizeof(float));
    int*   deg   = (int*)carve((size_t)Nn * sizeof(int));
    int*   rowp  = (int*)carve((size_t)(Nn + 1) * sizeof(int));
    int*   cur   = (int*)carve((size_t)Nn * sizeof(int));
    int*   bsums = (int*)carve(256 * sizeof(int));
    int*   esrc  = (int*)carve((size_t)Et * sizeof(int));
    (void)ws_size; (void)n_in; (void)out_size;

    const int nb = (Nn + 255) / 256;              // 196 (fits k_scan2's 256)
    const int ebk = (Et + 255) / 256;
    const int aggBlocks = (Nn * WAVE + 255) / 256;
    const int gemmB128 = (Nn + 31) / 32;
    const int gemmB64  = (Nn + 63) / 64;

    // graph build (must rerun every call; ws is re-poisoned)
    k_zero_i32<<<nb, 256, 0, stream>>>(deg, Nn);
    k_hist<<<ebk, 256, 0, stream>>>(ei, deg, E, Et);
    k_scan1<<<nb, 256, 0, stream>>>(deg, bsums, Nn);
    k_scan2<<<1, 256, 0, stream>>>(bsums, nb);
    k_scan3<<<nb, 256, 0, stream>>>(deg, bsums, rowp, cur, inv, Nn, Et);
    k_scatter<<<ebk, 256, 0, stream>>>(ei, cur, esrc, E, Et);

    // layer 1: GCN
    gemm_k128<128><<<gemmB128, 256, 0, stream>>>(x, W1, nullptr, bufA, Nn, 0);
    k_gcn_agg<<<aggBlocks, 256, 0, stream>>>(bufA, rowp, esrc, inv, b1, outH, Nn);
    // layer 2: GAT
    gemm_k128<128><<<gemmB128, 256, 0, stream>>>(outH, Wg1, nullptr, bufA, Nn, 0);
    k_alpha<<<aggBlocks, 256, 0, stream>>>(bufA, as1, ad1, alS, alD, Nn);
    k_gat_agg<<<aggBlocks, 256, 0, stream>>>(bufA, rowp, esrc, alS, alD, bg1, outH, Nn);
    // layer 3: GCN
    gemm_k128<128><<<gemmB128, 256, 0, stream>>>(outH, W2, nullptr, bufA, Nn, 0);
    k_gcn_agg<<<aggBlocks, 256, 0, stream>>>(bufA, rowp, esrc, inv, b2, outH, Nn);
    // layer 4: GAT
    gemm_k128<128><<<gemmB128, 256, 0, stream>>>(outH, Wg2, nullptr, bufA, Nn, 0);
    k_alpha<<<aggBlocks, 256, 0, stream>>>(bufA, as2, ad2, alS, alD, Nn);
    k_gat_agg<<<aggBlocks, 256, 0, stream>>>(bufA, rowp, esrc, alS, alD, bg2, outH, Nn);
    // head
    gemm_k128<64><<<gemmB64, 256, 0, stream>>>(outH, Wo, bo, outZ, Nn, 0);
}

// Round 2
// 620.570 us; speedup vs baseline: 1.0725x; 1.0725x over previous
//
#include <hip/hip_runtime.h>
#include <hip/hip_bf16.h>

// ---------------------------------------------------------------------------
// GNN: h = relu(GCN(x)); h = relu(GAT(h)); h = relu(GCN(h)); h = relu(GAT(h));
//      z = h @ Wo + bo.  Outputs: [h (N*128), z (N*64)] fp32.
// R2: aggregation kernels rebuilt for memory-level parallelism:
//   - lane owns feature pair (2l, 2l+1) -> one dwordx2 gather per edge
//   - 8-edge software pipeline (8 loads in flight before the FMA block)
//   - GAT softmax max+denom fused into one online pass
// ---------------------------------------------------------------------------

#define WAVE 64

// ------------------------------ graph build --------------------------------

__global__ void k_zero_i32(int* __restrict__ p, int n) {
    int i = blockIdx.x * 256 + threadIdx.x;
    if (i < n) p[i] = 0;
}

__global__ void k_hist(const int* __restrict__ ei, int* __restrict__ deg,
                       int E, int Et) {
    int e = blockIdx.x * 256 + threadIdx.x;
    if (e >= Et) return;
    int d = (e < E) ? ei[E + e] : (e - E);
    atomicAdd(&deg[d], 1);
}

__global__ void k_scan1(const int* __restrict__ deg, int* __restrict__ bs, int n) {
    __shared__ int tmp[256];
    int tid = threadIdx.x;
    int gid = blockIdx.x * 256 + tid;
    tmp[tid] = (gid < n) ? deg[gid] : 0;
    __syncthreads();
    for (int off = 128; off > 0; off >>= 1) {
        if (tid < off) tmp[tid] += tmp[tid + off];
        __syncthreads();
    }
    if (tid == 0) bs[blockIdx.x] = tmp[0];
}

__global__ void k_scan2(int* __restrict__ bs, int nb) {
    __shared__ int tmp[256];
    int tid = threadIdx.x;
    int v = (tid < nb) ? bs[tid] : 0;
    tmp[tid] = v;
    __syncthreads();
    for (int off = 1; off < 256; off <<= 1) {
        int t = (tid >= off) ? tmp[tid - off] : 0;
        __syncthreads();
        tmp[tid] += t;
        __syncthreads();
    }
    if (tid < nb) bs[tid] = tmp[tid] - v;   // exclusive
}

__global__ void k_scan3(const int* __restrict__ deg, const int* __restrict__ bs,
                        int* __restrict__ rowp, int* __restrict__ cur,
                        float* __restrict__ inv, int n, int total) {
    __shared__ int tmp[256];
    int tid = threadIdx.x;
    int gid = blockIdx.x * 256 + tid;
    int v = (gid < n) ? deg[gid] : 0;
    tmp[tid] = v;
    __syncthreads();
    for (int off = 1; off < 256; off <<= 1) {
        int t = (tid >= off) ? tmp[tid - off] : 0;
        __syncthreads();
        tmp[tid] += t;
        __syncthreads();
    }
    if (gid < n) {
        int rp = bs[blockIdx.x] + tmp[tid] - v;
        rowp[gid] = rp;
        cur[gid] = rp;
        inv[gid] = rsqrtf((float)v);
    }
    if (gid == 0) rowp[n] = total;
}

__global__ void k_scatter(const int* __restrict__ ei, int* __restrict__ cur,
                          int* __restrict__ esrc, int E, int Et) {
    int e = blockIdx.x * 256 + threadIdx.x;
    if (e >= Et) return;
    int s, d;
    if (e < E) { s = ei[e]; d = ei[E + e]; }
    else       { s = d = e - E; }
    int pos = atomicAdd(&cur[d], 1);
    esrc[pos] = s;
}

// ------------------------------ GEMM (fp32) --------------------------------

template <int NC>
__global__ __launch_bounds__(256) void gemm_k128(
    const float* __restrict__ A, const float* __restrict__ W,
    const float* __restrict__ bias, float* __restrict__ out,
    int M, int do_relu) {
    constexpr int TR = 4096 / NC;
    constexpr int CG = NC / 4;
    constexpr int AP = 132;
    __shared__ float Ws[64 * NC];
    __shared__ float As[TR * AP];

    const int tid = threadIdx.x;
    const int cg = tid % CG;
    const int rg = tid / CG;
    const int row0 = blockIdx.x * TR;

    for (int i = tid; i < TR * 32; i += 256) {
        int r = i >> 5, c4 = i & 31;
        int gr = row0 + r;
        float4 v = make_float4(0.f, 0.f, 0.f, 0.f);
        if (gr < M) v = ((const float4*)A)[(size_t)gr * 32 + c4];
        *((float4*)(As + r * AP + c4 * 4)) = v;
    }

    float acc[4][4] = {{0.f}};
    for (int half = 0; half < 2; ++half) {
        __syncthreads();
        for (int i = tid; i < 64 * NC / 4; i += 256)
            ((float4*)Ws)[i] = ((const float4*)W)[half * (64 * NC / 4) + i];
        __syncthreads();
#pragma unroll
        for (int k4 = 0; k4 < 16; ++k4) {
            float4 aa[4];
#pragma unroll
            for (int i = 0; i < 4; ++i)
                aa[i] = *((const float4*)(As + (rg * 4 + i) * AP + half * 64 + k4 * 4));
#pragma unroll
            for (int kk = 0; kk < 4; ++kk) {
                float4 w = ((const float4*)Ws)[(k4 * 4 + kk) * CG + cg];
#pragma unroll
                for (int i = 0; i < 4; ++i) {
                    float av = ((const float*)&aa[i])[kk];
                    acc[i][0] = fmaf(av, w.x, acc[i][0]);
                    acc[i][1] = fmaf(av, w.y, acc[i][1]);
                    acc[i][2] = fmaf(av, w.z, acc[i][2]);
                    acc[i][3] = fmaf(av, w.w, acc[i][3]);
                }
            }
        }
    }

    float4 b4 = make_float4(0.f, 0.f, 0.f, 0.f);
    if (bias) b4 = ((const float4*)bias)[cg];
#pragma unroll
    for (int i = 0; i < 4; ++i) {
        int gr = row0 + rg * 4 + i;
        if (gr < M) {
            float4 r;
            r.x = acc[i][0] + b4.x;
            r.y = acc[i][1] + b4.y;
            r.z = acc[i][2] + b4.z;
            r.w = acc[i][3] + b4.w;
            if (do_relu) {
                r.x = fmaxf(r.x, 0.f); r.y = fmaxf(r.y, 0.f);
                r.z = fmaxf(r.z, 0.f); r.w = fmaxf(r.w, 0.f);
            }
            ((float4*)out)[(size_t)gr * CG + cg] = r;
        }
    }
}

// --------------------------- aggregation kernels ---------------------------
// One wave per destination node; lane l owns features (2l, 2l+1).
// gather_accum: 8-edge software pipeline, one dwordx2 per edge per lane.

__device__ __forceinline__ void gather_accum(
    const float* __restrict__ xw, int lane, int cnt, int sid, float wgt,
    float& a0, float& a1) {
    int j = 0;
    for (; j + 8 <= cnt; j += 8) {
        float2 x[8];
        float w[8];
#pragma unroll
        for (int u = 0; u < 8; ++u) {
            int s = __shfl(sid, j + u);
            w[u] = __shfl(wgt, j + u);
            x[u] = *(const float2*)(xw + (size_t)s * 128 + lane * 2);
        }
#pragma unroll
        for (int u = 0; u < 8; ++u) {
            a0 = fmaf(w[u], x[u].x, a0);
            a1 = fmaf(w[u], x[u].y, a1);
        }
    }
    for (; j < cnt; ++j) {
        int s = __shfl(sid, j);
        float wj = __shfl(wgt, j);
        float2 xv = *(const float2*)(xw + (size_t)s * 128 + lane * 2);
        a0 = fmaf(wj, xv.x, a0);
        a1 = fmaf(wj, xv.y, a1);
    }
}

__global__ __launch_bounds__(256) void k_gcn_agg(
    const float* __restrict__ xw, const int* __restrict__ rowp,
    const int* __restrict__ esrc, const float* __restrict__ inv,
    const float* __restrict__ bias, float* __restrict__ out, int Nn) {
    int gid = blockIdx.x * 256 + threadIdx.x;
    int n = gid >> 6, lane = gid & 63;
    if (n >= Nn) return;
    int beg = rowp[n], end = rowp[n + 1];
    float invd = inv[n];
    float a0 = 0.f, a1 = 0.f;
    for (int base = beg; base < end; base += WAVE) {
        int e = base + lane;
        bool valid = (e < end);
        int sid = valid ? esrc[e] : 0;
        float c = valid ? invd * inv[sid] : 0.f;
        gather_accum(xw, lane, min(WAVE, end - base), sid, c, a0, a1);
    }
    float2 b = ((const float2*)bias)[lane];
    float2 r = make_float2(fmaxf(a0 + b.x, 0.f), fmaxf(a1 + b.y, 0.f));
    *(float2*)(out + (size_t)n * 128 + lane * 2) = r;
}

__global__ __launch_bounds__(256) void k_alpha(
    const float* __restrict__ xw, const float* __restrict__ asrc,
    const float* __restrict__ adst, float* __restrict__ s_out,
    float* __restrict__ d_out_, int Nn) {
    int gid = blockIdx.x * 256 + threadIdx.x;
    int n = gid >> 6, lane = gid & 63;
    if (n >= Nn) return;
    float2 xv = *(const float2*)(xw + (size_t)n * 128 + lane * 2);
    float2 sa = ((const float2*)asrc)[lane];
    float2 da = ((const float2*)adst)[lane];
    float s = fmaf(xv.y, sa.y, xv.x * sa.x);
    float d = fmaf(xv.y, da.y, xv.x * da.x);
#pragma unroll
    for (int off = 32; off > 0; off >>= 1) {
        s += __shfl_xor(s, off);
        d += __shfl_xor(d, off);
    }
    if (lane == 0) { s_out[n] = s; d_out_[n] = d; }
}

__global__ __launch_bounds__(256) void k_gat_agg(
    const float* __restrict__ xw, const int* __restrict__ rowp,
    const int* __restrict__ esrc, const float* __restrict__ as_,
    const float* __restrict__ ad_, const float* __restrict__ bias,
    float* __restrict__ out, int Nn) {
    int gid = blockIdx.x * 256 + threadIdx.x;
    int n = gid >> 6, lane = gid & 63;
    if (n >= Nn) return;
    int beg = rowp[n], end = rowp[n + 1];
    float adn = ad_[n];

    // fused online softmax (max + denom in one pass over edges)
    float m = -1e30f, ssum = 0.f;
    for (int e = beg + lane; e < end; e += WAVE) {
        float v = as_[esrc[e]] + adn;
        v = (v > 0.f) ? v : 0.2f * v;
        float mn = fmaxf(m, v);
        ssum = ssum * __expf(m - mn) + __expf(v - mn);
        m = mn;
    }
#pragma unroll
    for (int off = 32; off > 0; off >>= 1) {
        float mo = __shfl_xor(m, off);
        float so = __shfl_xor(ssum, off);
        float mn = fmaxf(m, mo);
        ssum = ssum * __expf(m - mn) + so * __expf(mo - mn);
        m = mn;
    }
    float rden = 1.f / ssum;

    // weighted aggregation (recompute logits; as_ is L2-resident)
    float a0 = 0.f, a1 = 0.f;
    for (int base = beg; base < end; base += WAVE) {
        int e = base + lane;
        bool valid = (e < end);
        int sid = valid ? esrc[e] : 0;
        float wgt = 0.f;
        if (valid) {
            float v = as_[sid] + adn;
            v = (v > 0.f) ? v : 0.2f * v;
            wgt = __expf(v - m) * rden;
        }
        gather_accum(xw, lane, min(WAVE, end - base), sid, wgt, a0, a1);
    }
    float2 b = ((const float2*)bias)[lane];
    float2 r = make_float2(fmaxf(a0 + b.x, 0.f), fmaxf(a1 + b.y, 0.f));
    *(float2*)(out + (size_t)n * 128 + lane * 2) = r;
}

// ------------------------------- launch ------------------------------------

extern "C" void kernel_launch(void* const* d_in, const int* in_sizes, int n_in,
                              void* d_out, int out_size, void* d_ws, size_t ws_size,
                              hipStream_t stream) {
    const float* x   = (const float*)d_in[0];
    const int*   ei  = (const int*)d_in[1];
    const float* W1  = (const float*)d_in[2];
    const float* b1  = (const float*)d_in[3];
    const float* Wg1 = (const float*)d_in[4];
    const float* as1 = (const float*)d_in[5];
    const float* ad1 = (const float*)d_in[6];
    const float* bg1 = (const float*)d_in[7];
    const float* W2  = (const float*)d_in[8];
    const float* b2  = (const float*)d_in[9];
    const float* Wg2 = (const float*)d_in[10];
    const float* as2 = (const float*)d_in[11];
    const float* ad2 = (const float*)d_in[12];
    const float* bg2 = (const float*)d_in[13];
    const float* Wo  = (const float*)d_in[14];
    const float* bo  = (const float*)d_in[15];

    const int Nn = in_sizes[0] / 128;
    const int E  = in_sizes[1] / 2;
    const int Et = E + Nn;
    const int H  = 128;

    float* outH = (float*)d_out;
    float* outZ = outH + (size_t)Nn * H;

    char* p = (char*)d_ws;
    auto carve = [&](size_t bytes) {
        char* r = p;
        p += (bytes + 255) & ~(size_t)255;
        return r;
    };
    float* bufA  = (float*)carve((size_t)Nn * H * sizeof(float));
    float* alS   = (float*)carve((size_t)Nn * sizeof(float));
    float* alD   = (float*)carve((size_t)Nn * sizeof(float));
    float* inv   = (float*)carve((size_t)Nn * sizeof(float));
    int*   deg   = (int*)carve((size_t)Nn * sizeof(int));
    int*   rowp  = (int*)carve((size_t)(Nn + 1) * sizeof(int));
    int*   cur   = (int*)carve((size_t)Nn * sizeof(int));
    int*   bsums = (int*)carve(256 * sizeof(int));
    int*   esrc  = (int*)carve((size_t)Et * sizeof(int));
    (void)ws_size; (void)n_in; (void)out_size;

    const int nb = (Nn + 255) / 256;
    const int ebk = (Et + 255) / 256;
    const int aggBlocks = (Nn * WAVE + 255) / 256;
    const int gemmB128 = (Nn + 31) / 32;
    const int gemmB64  = (Nn + 63) / 64;

    k_zero_i32<<<nb, 256, 0, stream>>>(deg, Nn);
    k_hist<<<ebk, 256, 0, stream>>>(ei, deg, E, Et);
    k_scan1<<<nb, 256, 0, stream>>>(deg, bsums, Nn);
    k_scan2<<<1, 256, 0, stream>>>(bsums, nb);
    k_scan3<<<nb, 256, 0, stream>>>(deg, bsums, rowp, cur, inv, Nn, Et);
    k_scatter<<<ebk, 256, 0, stream>>>(ei, cur, esrc, E, Et);

    gemm_k128<128><<<gemmB128, 256, 0, stream>>>(x, W1, nullptr, bufA, Nn, 0);
    k_gcn_agg<<<aggBlocks, 256, 0, stream>>>(bufA, rowp, esrc, inv, b1, outH, Nn);

    gemm_k128<128><<<gemmB128, 256, 0, stream>>>(outH, Wg1, nullptr, bufA, Nn, 0);
    k_alpha<<<aggBlocks, 256, 0, stream>>>(bufA, as1, ad1, alS, alD, Nn);
    k_gat_agg<<<aggBlocks, 256, 0, stream>>>(bufA, rowp, esrc, alS, alD, bg1, outH, Nn);

    gemm_k128<128><<<gemmB128, 256, 0, stream>>>(outH, W2, nullptr, bufA, Nn, 0);
    k_gcn_agg<<<aggBlocks, 256, 0, stream>>>(bufA, rowp, esrc, inv, b2, outH, Nn);

    gemm_k128<128><<<gemmB128, 256, 0, stream>>>(outH, Wg2, nullptr, bufA, Nn, 0);
    k_alpha<<<aggBlocks, 256, 0, stream>>>(bufA, as2, ad2, alS, alD, Nn);
    k_gat_agg<<<aggBlocks, 256, 0, stream>>>(bufA, rowp, esrc, alS, alD, bg2, outH, Nn);

    gemm_k128<64><<<gemmB64, 256, 0, stream>>>(outH, Wo, bo, outZ, Nn, 0);
}